// Round 5
// baseline (159.941 us; speedup 1.0000x reference)
//
#include <hip/hip_runtime.h>

// Balloon-Windkessel BOLD, T=1000, B=16384. alpha==1 decouples the system:
// (s,f) is an affine scan (2x2 const matrix), v,q are affine scans (scalar
// av) given f; only E(f) is pointwise-nonlinear. Parallelize T into 40
// chunks x 25 steps, 2 sims per thread (float2).
// KEY CHANGE vs R4: each thread loads its 25 float2 noise values ONCE into
// REGISTERS (full unroll -> static indices -> no scratch) and replays P2/P3
// from registers. Global z traffic: 3 passes -> 1 pass (196->65.5 MB reads).
// 512 blocks x 640 thr = 5120 waves = 20 waves/CU (2 blocks/CU, 10 KB LDS).

#define BATCH    16384
#define ROW2     (BATCH / 2)     // float2 elements per time-row
#define DT       0.01f
#define NOISE_AMP 0.01f
#define V0       0.02f
#define CHUNKS   40
#define CL       25              // 40 * 25 = 1000
#define LPR      16              // lanes per chunk-row (x2 sims = 32 sims/block)
#define NTHREADS (CHUNKS * LPR)  // 640
#define SCAND    6               // ceil(log2(40))

typedef float v2f __attribute__((ext_vector_type(2)));

#if __has_builtin(__builtin_amdgcn_exp2f)
#define EXP2F(x) __builtin_amdgcn_exp2f(x)
#else
#define EXP2F(x) exp2f(x)
#endif

__device__ __forceinline__ float uf(float x) {
    return __uint_as_float(__builtin_amdgcn_readfirstlane(__float_as_uint(x)));
}

struct D22 { double a, b, c, d; };
__device__ __forceinline__ D22 dmul(D22 x, D22 y) {
    D22 r;
    r.a = x.a * y.a + x.b * y.c;  r.b = x.a * y.b + x.b * y.d;
    r.c = x.c * y.a + x.d * y.c;  r.d = x.c * y.b + x.d * y.d;
    return r;
}

__global__ __launch_bounds__(NTHREADS, 5) void balloon_scan(
    const float* __restrict__ noise,
    const float* __restrict__ p_sigma,
    const float* __restrict__ p_mu,
    const float* __restrict__ p_lamb,
    const float* __restrict__ p_beta,
    const float* __restrict__ p_psi,
    const float* __restrict__ p_phi,
    const float* __restrict__ p_chi,
    float* __restrict__ out)
{
    const int tid  = threadIdx.x;
    const int lane = tid & (LPR - 1);
    const int cc   = tid >> 4;               // chunk 0..39

    const float sigma = uf(p_sigma[0]);
    const float mu    = uf(p_mu[0]);
    const float lamb  = uf(p_lamb[0]);
    const float beta  = uf(p_beta[0]);
    const float psi   = uf(p_psi[0]);
    const float phi   = uf(p_phi[0]);
    const float chi   = uf(p_chi[0]);

    // fp32 step constants (forms identical to validated R4)
    const float as_   = 1.0f - DT * sigma;
    const float dtn   = DT * NOISE_AMP;
    const float dtm   = DT * mu;
    const float dt_il = uf((float)(0.01 / (double)lamb));
    const float av    = 1.0f - dt_il;
    const float kq    = uf(dt_il / beta);
    const float lc    = uf(log2f(1.0f - beta));
    const float c0 = V0 * (phi + psi + chi), c1 = V0 * phi, c2 = V0 * psi, c3 = V0 * chi;

    // chunk-power weights in f64: A^(25*2^j), av^(25*2^j)
    D22 A; A.a = 1.0 - 0.01 * (double)sigma; A.b = -0.01 * (double)mu;
           A.c = 0.01;                       A.d = 1.0;
    D22 A2 = dmul(A, A), A4 = dmul(A2, A2), A8 = dmul(A4, A4), A16 = dmul(A8, A8);
    D22 P  = dmul(dmul(A16, A8), A);        // A^25
    double avd = 1.0 - 0.01 / (double)lamb;
    double av2 = avd * avd, av4 = av2 * av2, av8 = av4 * av4, av16 = av8 * av8;
    double ap  = av16 * av8 * avd;          // av^25

    float M11[SCAND], M12[SCAND], M21[SCAND], M22[SCAND], AVP[SCAND];
#pragma unroll
    for (int j = 0; j < SCAND; ++j) {
        M11[j] = uf((float)P.a); M12[j] = uf((float)P.b);
        M21[j] = uf((float)P.c); M22[j] = uf((float)P.d);
        AVP[j] = uf((float)ap);
        P = dmul(P, P); ap = ap * ap;
    }

    // homogeneous parts at chunk start: A^(25*cc)*(0,1)^T, av^(25*cc)
    float ws = 0.0f, wf = 1.0f, avc = 1.0f;
#pragma unroll
    for (int j = 0; j < SCAND; ++j) {
        if ((cc >> j) & 1) {
            const float t = __builtin_fmaf(M11[j], ws, M12[j] * wf);
            wf = __builtin_fmaf(M21[j], ws, M22[j] * wf);
            ws = t; avc *= AVP[j];
        }
    }

    // canonical per-step ops (P2 and P3 MUST share these forms exactly)
    auto sfstep = [&](float& s, float& f, float zz) {
        const float s2 = __builtin_fmaf(as_, s,
                         __builtin_fmaf(dtn, zz,
                         __builtin_fmaf(-dtm, f, dtm)));
        f = __builtin_fmaf(DT, s, f);
        s = s2;
    };
    auto vqfwd = [&](float f_, float& accv, float& accq) {
        const float invf = __builtin_amdgcn_rcpf(f_);
        const float e2   = EXP2F(lc * invf);
        const float t1   = __builtin_fmaf(-f_, e2, f_);   // f*E(f)
        accv = __builtin_fmaf(av, accv, dt_il * f_);
        accq = __builtin_fmaf(av, accq, kq * t1);
    };

    __shared__ float4 ssc[NTHREADS];

    const v2f* zg = (const v2f*)noise + (cc * CL) * ROW2 + blockIdx.x * LPR + lane;
    v2f z[CL];                              // 50 VGPRs of noise, loaded once

    // ---------------- P1: load z + (s,f) particular aggregate ----------------
    float rs0 = 0.f, rf0 = 0.f, rs1 = 0.f, rf1 = 0.f;
#pragma unroll
    for (int j = 0; j < CL; ++j) {
        z[j] = zg[j * ROW2];
        sfstep(rs0, rf0, z[j].x);
        sfstep(rs1, rf1, z[j].y);
    }

    // ---------------- scan1: inclusive over chunks, 2x2 weights ----------------
    ssc[tid] = make_float4(rs0, rf0, rs1, rf1);
    __syncthreads();
#pragma unroll
    for (int j = 0; j < SCAND; ++j) {
        const int off = 1 << j;
        const bool has = (cc >= off);
        float4 n = make_float4(0.f, 0.f, 0.f, 0.f);
        if (has) n = ssc[tid - off * LPR];
        __syncthreads();
        if (has) {
            rs0 = __builtin_fmaf(M11[j], n.x, __builtin_fmaf(M12[j], n.y, rs0));
            rf0 = __builtin_fmaf(M21[j], n.x, __builtin_fmaf(M22[j], n.y, rf0));
            rs1 = __builtin_fmaf(M11[j], n.z, __builtin_fmaf(M12[j], n.w, rs1));
            rf1 = __builtin_fmaf(M21[j], n.z, __builtin_fmaf(M22[j], n.w, rf1));
            ssc[tid] = make_float4(rs0, rf0, rs1, rf1);
        }
        __syncthreads();
    }
    float s0a = ws, f0a = wf, s0b = ws, f0b = wf;
    if (cc > 0) {
        const float4 pr = ssc[tid - LPR];
        s0a += pr.x; f0a += pr.y; s0b += pr.z; f0b += pr.w;
    }
    __syncthreads();        // ssc reuse for scan2

    // ---------------- P2: replay f from registers, v/q aggregates ----------------
    float sa = s0a, fa = f0a, sb = s0b, fb = f0b;
    float Rv0 = 0.f, Rq0 = 0.f, Rv1 = 0.f, Rq1 = 0.f;
#pragma unroll
    for (int j = 0; j < CL; ++j) {
        vqfwd(fa, Rv0, Rq0);
        vqfwd(fb, Rv1, Rq1);
        sfstep(sa, fa, z[j].x);
        sfstep(sb, fb, z[j].y);
    }

    // ---------------- scan2: scalar weights av^(25*2^j) ----------------
    ssc[tid] = make_float4(Rv0, Rq0, Rv1, Rq1);
    __syncthreads();
#pragma unroll
    for (int j = 0; j < SCAND; ++j) {
        const int off = 1 << j;
        const bool has = (cc >= off);
        float4 n = make_float4(0.f, 0.f, 0.f, 0.f);
        if (has) n = ssc[tid - off * LPR];
        __syncthreads();
        if (has) {
            Rv0 = __builtin_fmaf(AVP[j], n.x, Rv0);
            Rq0 = __builtin_fmaf(AVP[j], n.y, Rq0);
            Rv1 = __builtin_fmaf(AVP[j], n.z, Rv1);
            Rq1 = __builtin_fmaf(AVP[j], n.w, Rq1);
            ssc[tid] = make_float4(Rv0, Rq0, Rv1, Rq1);
        }
        __syncthreads();
    }
    float va = avc, qa = avc, vb = avc, qb = avc;   // v0 = q0 = 1
    if (cc > 0) {
        const float4 pr = ssc[tid - LPR];
        va += pr.x; qa += pr.y; vb += pr.z; qb += pr.w;
    }

    // ---------------- P3: replay from registers, emit y ----------------
    sa = s0a; fa = f0a; sb = s0b; fb = f0b;
    v2f* og = (v2f*)out + (cc * CL) * ROW2 + blockIdx.x * LPR + lane;
#pragma unroll
    for (int j = 0; j < CL; ++j) {
        vqfwd(fa, va, qa);                    // va,qa -> v2,q2 of step t
        vqfwd(fb, vb, qb);
        sfstep(sa, fa, z[j].x);
        sfstep(sb, fb, z[j].y);

        const float ia = __builtin_amdgcn_rcpf(va);
        const float ib = __builtin_amdgcn_rcpf(vb);
        v2f y2;
        y2.x = __builtin_fmaf(-c2, qa * ia,
               __builtin_fmaf(-c3, va,
               __builtin_fmaf(-c1, qa, c0)));
        y2.y = __builtin_fmaf(-c2, qb * ib,
               __builtin_fmaf(-c3, vb,
               __builtin_fmaf(-c1, qb, c0)));
        __builtin_nontemporal_store(y2, og + j * ROW2);
    }
}

extern "C" void kernel_launch(void* const* d_in, const int* in_sizes, int n_in,
                              void* d_out, int out_size, void* d_ws, size_t ws_size,
                              hipStream_t stream) {
    const float* noise   = (const float*)d_in[0];
    const float* p_sigma = (const float*)d_in[1];
    const float* p_mu    = (const float*)d_in[2];
    const float* p_lamb  = (const float*)d_in[3];
    const float* p_beta  = (const float*)d_in[4];
    const float* p_psi   = (const float*)d_in[5];
    const float* p_phi   = (const float*)d_in[6];
    const float* p_chi   = (const float*)d_in[7];

    balloon_scan<<<BATCH / (2 * LPR), NTHREADS, 0, stream>>>(
        noise, p_sigma, p_mu, p_lamb, p_beta, p_psi, p_phi, p_chi,
        (float*)d_out);
}

// Round 6
// 154.690 us; speedup vs baseline: 1.0339x; 1.0339x over previous
//
#include <hip/hip_runtime.h>

// Balloon-Windkessel BOLD, T=1000, B=16384. alpha==1 decouples the system:
// (s,f) is an affine scan (2x2 const matrix); v,q are affine scans (scalar
// av=1-DT/lamb) given f; only E(f) is pointwise-nonlinear. Parallelize T:
// 40 chunks x 25 steps, ONE sim per thread (R5's 2 sims/thread spilled its
// 50-VGPR z-array under the launch_bounds cap -> +40MB scratch traffic).
//   P1: load z[25] into REGISTERS once + (s,f) chunk aggregate
//   scan1 (LDS, 2x2 weights A^(25*2^j))       -> chunk-start (s,f)
//   P2: replay f, overwrite z[j] := f_j, accumulate v,q aggregates
//   scan2 (scalar av^(25*2^j))                -> chunk-start (v,q)
//   P3: consume stashed f_j, emit y            (no global reads)
// Global traffic = exactly one read + one write pass (131 MB, ~21 us floor).
// 1024 blocks x 640 thr; ~56 VGPR -> 2-3 blocks/CU resident.

#define BATCH    16384
#define DT       0.01f
#define NOISE_AMP 0.01f
#define V0       0.02f
#define CHUNKS   40
#define CL       25              // 40 * 25 = 1000
#define LPR      16              // lanes (sims) per chunk-row
#define NTHREADS (CHUNKS * LPR)  // 640
#define SCAND    6               // ceil(log2(40))

#if __has_builtin(__builtin_amdgcn_exp2f)
#define EXP2F(x) __builtin_amdgcn_exp2f(x)
#else
#define EXP2F(x) exp2f(x)
#endif

__device__ __forceinline__ float uf(float x) {
    return __uint_as_float(__builtin_amdgcn_readfirstlane(__float_as_uint(x)));
}

struct D22 { double a, b, c, d; };
__device__ __forceinline__ D22 dmul(D22 x, D22 y) {
    D22 r;
    r.a = x.a * y.a + x.b * y.c;  r.b = x.a * y.b + x.b * y.d;
    r.c = x.c * y.a + x.d * y.c;  r.d = x.c * y.b + x.d * y.d;
    return r;
}

__global__ __launch_bounds__(NTHREADS, 6) void balloon_scan(
    const float* __restrict__ noise,
    const float* __restrict__ p_sigma,
    const float* __restrict__ p_mu,
    const float* __restrict__ p_lamb,
    const float* __restrict__ p_beta,
    const float* __restrict__ p_psi,
    const float* __restrict__ p_phi,
    const float* __restrict__ p_chi,
    float* __restrict__ out)
{
    const int tid  = threadIdx.x;
    const int lane = tid & (LPR - 1);
    const int cc   = tid >> 4;                       // chunk 0..39
    const int sim  = blockIdx.x * LPR + lane;

    const float sigma = uf(p_sigma[0]);
    const float mu    = uf(p_mu[0]);
    const float lamb  = uf(p_lamb[0]);
    const float beta  = uf(p_beta[0]);
    const float psi   = uf(p_psi[0]);
    const float phi   = uf(p_phi[0]);
    const float chi   = uf(p_chi[0]);

    // fp32 step constants (forms identical to validated R4/R5)
    const float as_   = 1.0f - DT * sigma;
    const float dtn   = DT * NOISE_AMP;
    const float dtm   = DT * mu;
    const float dt_il = uf((float)(0.01 / (double)lamb));
    const float av    = 1.0f - dt_il;
    const float kq    = uf(dt_il / beta);
    const float lc    = uf(log2f(1.0f - beta));
    const float c0 = V0 * (phi + psi + chi), c1 = V0 * phi, c2 = V0 * psi, c3 = V0 * chi;

    // chunk-power weights in f64: A^(25*2^j), av^(25*2^j)
    D22 A; A.a = 1.0 - 0.01 * (double)sigma; A.b = -0.01 * (double)mu;
           A.c = 0.01;                       A.d = 1.0;
    D22 A2 = dmul(A, A), A4 = dmul(A2, A2), A8 = dmul(A4, A4), A16 = dmul(A8, A8);
    D22 P  = dmul(dmul(A16, A8), A);                 // A^25
    double avd = 1.0 - 0.01 / (double)lamb;
    double av2 = avd * avd, av4 = av2 * av2, av8 = av4 * av4, av16 = av8 * av8;
    double ap  = av16 * av8 * avd;                   // av^25

    float M11[SCAND], M12[SCAND], M21[SCAND], M22[SCAND], AVP[SCAND];
#pragma unroll
    for (int j = 0; j < SCAND; ++j) {
        M11[j] = uf((float)P.a); M12[j] = uf((float)P.b);
        M21[j] = uf((float)P.c); M22[j] = uf((float)P.d);
        AVP[j] = uf((float)ap);
        P = dmul(P, P); ap = ap * ap;
    }

    // homogeneous parts at chunk start: A^(25*cc)*(0,1)^T, av^(25*cc)
    float ws = 0.0f, wf = 1.0f, avc = 1.0f;
#pragma unroll
    for (int j = 0; j < SCAND; ++j) {
        if ((cc >> j) & 1) {
            const float t = __builtin_fmaf(M11[j], ws, M12[j] * wf);
            wf = __builtin_fmaf(M21[j], ws, M22[j] * wf);
            ws = t; avc *= AVP[j];
        }
    }

    // canonical per-step ops (P1's replay in P2 must match exactly)
    auto sfstep = [&](float& s, float& f, float zz) {
        const float s2 = __builtin_fmaf(as_, s,
                         __builtin_fmaf(dtn, zz,
                         __builtin_fmaf(-dtm, f, dtm)));
        f = __builtin_fmaf(DT, s, f);
        s = s2;
    };
    auto vqfwd = [&](float f_, float& accv, float& accq) {
        const float invf = __builtin_amdgcn_rcpf(f_);
        const float e2   = EXP2F(lc * invf);
        const float t1   = __builtin_fmaf(-f_, e2, f_);   // f*E(f)
        accv = __builtin_fmaf(av, accv, dt_il * f_);
        accq = __builtin_fmaf(av, accq, kq * t1);
    };

    __shared__ float2 ss[NTHREADS];                  // 5 KB

    const float* zp = noise + (cc * CL) * BATCH + sim;
    float z[CL];                                     // 25 VGPRs, loaded ONCE

    // ---------------- P1: load z + (s,f) particular aggregate ----------------
    float rs = 0.f, rf = 0.f;
#pragma unroll
    for (int j = 0; j < CL; ++j) {
        z[j] = zp[j * BATCH];
        sfstep(rs, rf, z[j]);
    }

    // ---------------- scan1: inclusive over chunks, 2x2 weights ----------------
    ss[tid] = make_float2(rs, rf);
    __syncthreads();
#pragma unroll
    for (int j = 0; j < SCAND; ++j) {
        const int off = 1 << j;
        const bool has = (cc >= off);
        float2 n = make_float2(0.f, 0.f);
        if (has) n = ss[tid - off * LPR];
        __syncthreads();
        if (has) {
            rs = __builtin_fmaf(M11[j], n.x, __builtin_fmaf(M12[j], n.y, rs));
            rf = __builtin_fmaf(M21[j], n.x, __builtin_fmaf(M22[j], n.y, rf));
            ss[tid] = make_float2(rs, rf);
        }
        __syncthreads();
    }
    float s = ws, f = wf;                            // chunk-start state
    if (cc > 0) {
        const float2 pr = ss[tid - LPR];
        s += pr.x; f += pr.y;
    }
    __syncthreads();                                 // ss reused for scan2

    // ---------------- P2: replay f, stash f_j into z[j], v/q aggregates ----------------
    float Rv = 0.f, Rq = 0.f;
#pragma unroll
    for (int j = 0; j < CL; ++j) {
        const float zz = z[j];
        z[j] = f;                                    // stash f_j for P3
        vqfwd(f, Rv, Rq);
        sfstep(s, f, zz);
    }

    // ---------------- scan2: scalar weights av^(25*2^j) ----------------
    ss[tid] = make_float2(Rv, Rq);
    __syncthreads();
#pragma unroll
    for (int j = 0; j < SCAND; ++j) {
        const int off = 1 << j;
        const bool has = (cc >= off);
        float2 n = make_float2(0.f, 0.f);
        if (has) n = ss[tid - off * LPR];
        __syncthreads();
        if (has) {
            Rv = __builtin_fmaf(AVP[j], n.x, Rv);
            Rq = __builtin_fmaf(AVP[j], n.y, Rq);
            ss[tid] = make_float2(Rv, Rq);
        }
        __syncthreads();
    }
    float v = avc, q = avc;                          // v0 = q0 = 1
    if (cc > 0) {
        const float2 pr = ss[tid - LPR];
        v += pr.x; q += pr.y;
    }

    // ---------------- P3: consume stashed f_j, emit y (no loads) ----------------
    float* op = out + (cc * CL) * BATCH + sim;
#pragma unroll
    for (int j = 0; j < CL; ++j) {
        const float fj = z[j];
        vqfwd(fj, v, q);                             // v,q -> state after step j
        const float iv = __builtin_amdgcn_rcpf(v);
        const float y = __builtin_fmaf(-c2, q * iv,
                        __builtin_fmaf(-c3, v,
                        __builtin_fmaf(-c1, q, c0)));
        __builtin_nontemporal_store(y, op + j * BATCH);
    }
}

extern "C" void kernel_launch(void* const* d_in, const int* in_sizes, int n_in,
                              void* d_out, int out_size, void* d_ws, size_t ws_size,
                              hipStream_t stream) {
    const float* noise   = (const float*)d_in[0];
    const float* p_sigma = (const float*)d_in[1];
    const float* p_mu    = (const float*)d_in[2];
    const float* p_lamb  = (const float*)d_in[3];
    const float* p_beta  = (const float*)d_in[4];
    const float* p_psi   = (const float*)d_in[5];
    const float* p_phi   = (const float*)d_in[6];
    const float* p_chi   = (const float*)d_in[7];

    balloon_scan<<<BATCH / LPR, NTHREADS, 0, stream>>>(
        noise, p_sigma, p_mu, p_lamb, p_beta, p_psi, p_phi, p_chi,
        (float*)d_out);
}